// Round 3
// baseline (1167.902 us; speedup 1.0000x reference)
//
#include <hip/hip_runtime.h>
#include <math.h>

#define T_TOKENS    16384
#define D_MODEL     2048
#define NUM_EXPERTS 256
#define TOP_K       8
#define MARGIN      6e-5f

// d_out layout (floats): idx | weights | affinities | loss
#define OUT_IDX  0
#define OUT_W    (T_TOKENS * TOP_K)
#define OUT_AFF  (2 * T_TOKENS * TOP_K)
#define OUT_LOSS (2 * T_TOKENS * TOP_K + T_TOKENS * NUM_EXPERTS)

// ws layout (bytes)
#define WS_M64_B   ((size_t)0)                                    // double[256*2048] 4MB
#define WS_MH_B    (WS_M64_B + (size_t)NUM_EXPERTS * D_MODEL * 8) // bf16  1MB
#define WS_ML_B    (WS_MH_B  + (size_t)NUM_EXPERTS * D_MODEL * 2) // bf16  1MB
#define WS_SUMP_B  (WS_ML_B  + (size_t)NUM_EXPERTS * D_MODEL * 2) // double[256]
#define WS_CNT_B   (WS_SUMP_B + NUM_EXPERTS * 8)                  // float[256]
#define WS_NMARG_B (WS_CNT_B  + NUM_EXPERTS * 4)                  // int
#define WS_LIST_B  (WS_NMARG_B + 16)                              // int[16384]

typedef __attribute__((ext_vector_type(8))) short short8;
typedef __attribute__((ext_vector_type(4))) float f32x4;

__device__ __forceinline__ unsigned short bf16_rne(float x) {
    unsigned u = __float_as_uint(x);
    u += 0x7FFFu + ((u >> 16) & 1u);
    return (unsigned short)(u >> 16);
}
__device__ __forceinline__ float bf16_f32(unsigned short h) {
    return __uint_as_float(((unsigned)h) << 16);
}

// ---------------------------------------------------------------------------
// Kernel A: M = C @ W. f64 accumulate (f32 LDS staging, exact). Outputs
// M64 (for recheck) + bf16 split Mh/Ml (for the MFMA fast path).
// tile 32e x 64k, BK=32, grid (32,8)=256 blocks.
// ---------------------------------------------------------------------------
__global__ __launch_bounds__(256) void cw_gemm_f64(
    const float* __restrict__ C, const float* __restrict__ W,
    double* __restrict__ M64, unsigned short* __restrict__ Mh,
    unsigned short* __restrict__ Ml)
{
    __shared__ float Cs[32][33];  // [d][e]
    __shared__ float Ws[32][68];  // [d][k]

    const int tid = threadIdx.x;
    const int tx = tid & 15;
    const int ty = tid >> 4;
    const int e0 = blockIdx.y * 32;
    const int k0 = blockIdx.x * 64;

    double acc[2][4] = {{0,0,0,0},{0,0,0,0}};

    for (int d0 = 0; d0 < D_MODEL; d0 += 32) {
        {
            const int e = tid >> 3, d4 = (tid & 7) * 4;
            const float4 v = *(const float4*)(C + (size_t)(e0 + e) * D_MODEL + d0 + d4);
            Cs[d4 + 0][e] = v.x; Cs[d4 + 1][e] = v.y;
            Cs[d4 + 2][e] = v.z; Cs[d4 + 3][e] = v.w;
        }
        #pragma unroll
        for (int r = 0; r < 2; ++r) {
            const int idx = tid + r * 256;
            const int d = idx >> 4, k4 = (idx & 15) * 4;
            *(float4*)&Ws[d][k4] =
                *(const float4*)(W + (size_t)(d0 + d) * D_MODEL + k0 + k4);
        }
        __syncthreads();
        #pragma unroll
        for (int dd = 0; dd < 32; ++dd) {
            const double a0 = (double)Cs[dd][ty * 2 + 0];
            const double a1 = (double)Cs[dd][ty * 2 + 1];
            const float4 b4 = *(const float4*)&Ws[dd][tx * 4];
            const double b[4] = {(double)b4.x, (double)b4.y, (double)b4.z, (double)b4.w};
            #pragma unroll
            for (int j = 0; j < 4; ++j) { acc[0][j] += a0 * b[j]; acc[1][j] += a1 * b[j]; }
        }
        __syncthreads();
    }
    #pragma unroll
    for (int i = 0; i < 2; ++i) {
        const int e = e0 + ty * 2 + i;
        #pragma unroll
        for (int j = 0; j < 4; ++j) {
            const size_t idx = (size_t)e * D_MODEL + k0 + tx * 4 + j;
            const double v = acc[i][j];
            M64[idx] = v;
            const float f = (float)v;
            const unsigned short hi = bf16_rne(f);
            const unsigned short lo = bf16_rne(f - bf16_f32(hi));
            Mh[idx] = hi; Ml[idx] = lo;
        }
    }
}

// ---------------------------------------------------------------------------
// Kernel B: fast-path affinities via bf16-split MFMA (4 combos, f32 accum).
// tile 64t x 256e, BK=32, grid 256 blocks, 4 waves (wave-tile 64t x 64e).
// Also writes f32 aff and accumulates sumP (f64 atomics).
// ---------------------------------------------------------------------------
__global__ __launch_bounds__(256) void affinity_mfma(
    const float* __restrict__ H, const unsigned short* __restrict__ Mh,
    const unsigned short* __restrict__ Ml,
    float* __restrict__ aff, double* __restrict__ sumP)
{
    __shared__ unsigned short sHh[64][40], sHl[64][40];   // 5.0 KiB x2
    __shared__ unsigned short sMh[256][40], sMl[256][40]; // 20 KiB x2

    const int tid = threadIdx.x;
    const int lane = tid & 63, wv = tid >> 6;
    const int m = lane & 15, quad = lane >> 4;
    const int t0 = blockIdx.x * 64;

    // staging coords
    const int srow = tid >> 2;        // 0..63 H row
    const int kq4 = (tid & 3) * 4;    // H k sub-base
    const int me = tid >> 2;          // M row within 64-row pass
    const int mk8 = (tid & 3) * 8;    // M k base (8 bf16 = 16B)

    f32x4 acc[4][4];
    #pragma unroll
    for (int i = 0; i < 4; ++i)
        #pragma unroll
        for (int j = 0; j < 4; ++j) acc[i][j] = (f32x4){0.f, 0.f, 0.f, 0.f};

    for (int kc = 0; kc < 64; ++kc) {
        const int k0 = kc * 32;
        // stage H 64x32 (f32 -> bf16 hi/lo)
        #pragma unroll
        for (int c = 0; c < 2; ++c) {
            const float4 v = *(const float4*)(H + (size_t)(t0 + srow) * D_MODEL + k0 + kq4 + c * 16);
            unsigned short h0 = bf16_rne(v.x), h1 = bf16_rne(v.y),
                           h2 = bf16_rne(v.z), h3 = bf16_rne(v.w);
            unsigned short l0 = bf16_rne(v.x - bf16_f32(h0)),
                           l1 = bf16_rne(v.y - bf16_f32(h1)),
                           l2 = bf16_rne(v.z - bf16_f32(h2)),
                           l3 = bf16_rne(v.w - bf16_f32(h3));
            uint2 ph, pl;
            ph.x = (unsigned)h0 | ((unsigned)h1 << 16); ph.y = (unsigned)h2 | ((unsigned)h3 << 16);
            pl.x = (unsigned)l0 | ((unsigned)l1 << 16); pl.y = (unsigned)l2 | ((unsigned)l3 << 16);
            *(uint2*)&sHh[srow][kq4 + c * 16] = ph;
            *(uint2*)&sHl[srow][kq4 + c * 16] = pl;
        }
        // stage M 256x32 (bf16 direct)
        #pragma unroll
        for (int p = 0; p < 4; ++p) {
            const int e = p * 64 + me;
            const size_t g = (size_t)e * D_MODEL + k0 + mk8;
            *(uint4*)&sMh[e][mk8] = *(const uint4*)(Mh + g);
            *(uint4*)&sMl[e][mk8] = *(const uint4*)(Ml + g);
        }
        __syncthreads();

        short8 ah[4], al[4], bh[4], bl[4];
        #pragma unroll
        for (int i = 0; i < 4; ++i) {
            ah[i] = *(const short8*)&sHh[i * 16 + m][quad * 8];
            al[i] = *(const short8*)&sHl[i * 16 + m][quad * 8];
        }
        #pragma unroll
        for (int j = 0; j < 4; ++j) {
            bh[j] = *(const short8*)&sMh[wv * 64 + j * 16 + m][quad * 8];
            bl[j] = *(const short8*)&sMl[wv * 64 + j * 16 + m][quad * 8];
        }
        #pragma unroll
        for (int i = 0; i < 4; ++i)
            #pragma unroll
            for (int j = 0; j < 4; ++j) {
                acc[i][j] = __builtin_amdgcn_mfma_f32_16x16x32_bf16(ah[i], bh[j], acc[i][j], 0, 0, 0);
                acc[i][j] = __builtin_amdgcn_mfma_f32_16x16x32_bf16(ah[i], bl[j], acc[i][j], 0, 0, 0);
                acc[i][j] = __builtin_amdgcn_mfma_f32_16x16x32_bf16(al[i], bh[j], acc[i][j], 0, 0, 0);
                acc[i][j] = __builtin_amdgcn_mfma_f32_16x16x32_bf16(al[i], bl[j], acc[i][j], 0, 0, 0);
            }
        __syncthreads();
    }

    // epilogue: aff stores + sigmoid column sums
    #pragma unroll
    for (int j = 0; j < 4; ++j) {
        const int e = wv * 64 + j * 16 + m;
        float colsum = 0.f;
        #pragma unroll
        for (int i = 0; i < 4; ++i) {
            const int tbase = t0 + i * 16 + quad * 4;
            #pragma unroll
            for (int r = 0; r < 4; ++r) {
                const float v = acc[i][j][r];
                aff[(size_t)(tbase + r) * NUM_EXPERTS + e] = v;
                colsum += 1.f / (1.f + expf(-v));
            }
        }
        colsum += __shfl_xor(colsum, 16, 64);
        colsum += __shfl_xor(colsum, 32, 64);
        if (quad == 0) atomicAdd(&sumP[e], (double)colsum);
    }
}

// ---------------------------------------------------------------------------
// Kernel C: fast top-9 (f32) with margin test. Non-marginal tokens write
// idx/weights/counts; marginal tokens go to the recheck list.
// ---------------------------------------------------------------------------
__global__ __launch_bounds__(256) void topk_margin(
    const float* __restrict__ aff, const float* __restrict__ bias,
    float* __restrict__ out_idx, float* __restrict__ out_w,
    float* __restrict__ counts, int* __restrict__ nmarg, int* __restrict__ list)
{
    const int lane = threadIdx.x & 63;
    const int wv = threadIdx.x >> 6;
    const int t = blockIdx.x * 4 + wv;

    const float4 av = *(const float4*)(aff + (size_t)t * NUM_EXPERTS + lane * 4);
    const float4 bv = *(const float4*)(bias + lane * 4);
    float g[4], s[4];
    g[0] = 1.f / (1.f + expf(-av.x)); s[0] = g[0] + bv.x;
    g[1] = 1.f / (1.f + expf(-av.y)); s[1] = g[1] + bv.y;
    g[2] = 1.f / (1.f + expf(-av.z)); s[2] = g[2] + bv.z;
    g[3] = 1.f / (1.f + expf(-av.w)); s[3] = g[3] + bv.w;

    float wsum = 0.f, my_g = 0.f, prev = 0.f, minGap = 1e30f;
    int my_i = 0;

    for (int it = 0; it < 9; ++it) {
        float bs = s[0], bg = g[0]; int bi = lane * 4;
        #pragma unroll
        for (int j = 1; j < 4; ++j)
            if (s[j] > bs) { bs = s[j]; bg = g[j]; bi = lane * 4 + j; }
        #pragma unroll
        for (int off = 1; off < 64; off <<= 1) {
            const float os = __shfl_xor(bs, off, 64);
            const float og = __shfl_xor(bg, off, 64);
            const int   oi = __shfl_xor(bi, off, 64);
            if (os > bs || (os == bs && oi < bi)) { bs = os; bg = og; bi = oi; }
        }
        if (it < TOP_K) {
            wsum += bg;
            if (lane == it) { my_i = bi; my_g = bg; }
        }
        if (it > 0) minGap = fminf(minGap, prev - bs);
        prev = bs;
        if ((bi >> 2) == lane) s[bi & 3] = -1e30f;
    }

    if (minGap < MARGIN) {
        if (lane == 0) { const int pos = atomicAdd(nmarg, 1); list[pos] = t; }
    } else {
        const float inv = 1.f / (wsum + 1e-10f);
        if (lane < TOP_K) {
            out_idx[(size_t)t * TOP_K + lane] = (float)my_i;
            out_w[(size_t)t * TOP_K + lane] = my_g * inv;
            atomicAdd(&counts[my_i], 1.0f);
        }
    }
}

// ---------------------------------------------------------------------------
// Kernel R: exact f64 recheck for marginal tokens (4 tokens/block).
// aff64 = h @ M64^T, then f64 top-8 (identical decision path to round-2).
// ---------------------------------------------------------------------------
__global__ __launch_bounds__(256) void recheck_kernel(
    const float* __restrict__ H, const double* __restrict__ M64,
    const float* __restrict__ bias, const int* __restrict__ list,
    const int* __restrict__ nmarg, float* __restrict__ out_idx,
    float* __restrict__ out_w, float* __restrict__ counts)
{
    __shared__ float hs4[D_MODEL][4];        // [k][tok] transposed, 32 KiB
    __shared__ double affs[4][NUM_EXPERTS];  // 8 KiB

    const int n = *nmarg;
    const int lane = threadIdx.x & 63, wv = threadIdx.x >> 6;

    for (int base = (int)blockIdx.x * 4; base < n; base += (int)gridDim.x * 4) {
        const int ntok = min(4, n - base);
        // load h rows transposed (zero-fill unused slots)
        for (int sidx = threadIdx.x; sidx < 4 * (D_MODEL / 4); sidx += 256) {
            const int tok = sidx >> 9;          // 512 float4 per row
            const int kq = (sidx & 511) * 4;
            float4 v = {0.f, 0.f, 0.f, 0.f};
            if (tok < ntok) {
                const int t = list[base + tok];
                v = *(const float4*)(H + (size_t)t * D_MODEL + kq);
            }
            hs4[kq + 0][tok] = v.x; hs4[kq + 1][tok] = v.y;
            hs4[kq + 2][tok] = v.z; hs4[kq + 3][tok] = v.w;
        }
        __syncthreads();

        for (int eq = 0; eq < 16; ++eq) {
            const int ebase = wv * 64 + eq * 4;
            double acc[4][4];
            #pragma unroll
            for (int c = 0; c < 4; ++c)
                #pragma unroll
                for (int tk = 0; tk < 4; ++tk) acc[c][tk] = 0.0;
            #pragma unroll 4
            for (int j = 0; j < 32; ++j) {
                const int k = lane + 64 * j;
                const float4 hv = *(const float4*)&hs4[k][0];
                const double h0 = (double)hv.x, h1 = (double)hv.y,
                             h2 = (double)hv.z, h3 = (double)hv.w;
                #pragma unroll
                for (int c = 0; c < 4; ++c) {
                    const double mv = M64[(size_t)(ebase + c) * D_MODEL + k];
                    acc[c][0] += mv * h0; acc[c][1] += mv * h1;
                    acc[c][2] += mv * h2; acc[c][3] += mv * h3;
                }
            }
            #pragma unroll
            for (int c = 0; c < 4; ++c)
                #pragma unroll
                for (int tk = 0; tk < 4; ++tk) {
                    double v = acc[c][tk];
                    #pragma unroll
                    for (int off = 1; off < 64; off <<= 1) v += __shfl_xor(v, off, 64);
                    if (lane == 0) affs[tk][ebase + c] = v;
                }
        }
        __syncthreads();

        if (wv < ntok) {
            const int t = list[base + wv];
            double g[4], s[4];
            #pragma unroll
            for (int jj = 0; jj < 4; ++jj) {
                const int e = lane * 4 + jj;
                const double x = affs[wv][e];
                g[jj] = 1.0 / (1.0 + exp(-x));
                s[jj] = g[jj] + (double)bias[e];
            }
            double wsum = 0.0, my_g = 0.0;
            int my_i = 0;
            for (int it = 0; it < TOP_K; ++it) {
                double bs = s[0], bg = g[0]; int bi = lane * 4;
                #pragma unroll
                for (int j = 1; j < 4; ++j)
                    if (s[j] > bs) { bs = s[j]; bg = g[j]; bi = lane * 4 + j; }
                #pragma unroll
                for (int off = 1; off < 64; off <<= 1) {
                    const double os = __shfl_xor(bs, off, 64);
                    const double og = __shfl_xor(bg, off, 64);
                    const int    oi = __shfl_xor(bi, off, 64);
                    if (os > bs || (os == bs && oi < bi)) { bs = os; bg = og; bi = oi; }
                }
                wsum += bg;
                if (lane == it) { my_i = bi; my_g = bg; }
                if ((bi >> 2) == lane) s[bi & 3] = -1e300;
            }
            const double inv = 1.0 / (wsum + 1e-10);
            if (lane < TOP_K) {
                out_idx[(size_t)t * TOP_K + lane] = (float)my_i;
                out_w[(size_t)t * TOP_K + lane] = (float)(my_g * inv);
                atomicAdd(&counts[my_i], 1.0f);
            }
        }
        __syncthreads();
    }
}

// ---------------------------------------------------------------------------
// Kernel D: balance loss
// ---------------------------------------------------------------------------
__global__ __launch_bounds__(256) void loss_f64(
    const double* __restrict__ sumP, const float* __restrict__ counts,
    float* __restrict__ out_loss)
{
    __shared__ double red[256];
    const int e = threadIdx.x;
    red[e] = (double)counts[e] * sumP[e];
    __syncthreads();
    #pragma unroll
    for (int sft = 128; sft > 0; sft >>= 1) {
        if (e < sft) red[e] += red[e + sft];
        __syncthreads();
    }
    if (e == 0) {
        const double denom = (double)T_TOKENS * (double)TOP_K * (double)T_TOKENS;
        out_loss[0] = (float)(0.001 * ((double)NUM_EXPERTS / (double)TOP_K) * red[0] / denom);
    }
}

extern "C" void kernel_launch(void* const* d_in, const int* in_sizes, int n_in,
                              void* d_out, int out_size, void* d_ws, size_t ws_size,
                              hipStream_t stream) {
    (void)in_sizes; (void)n_in; (void)out_size; (void)ws_size;
    const float* hidden = (const float*)d_in[0];
    const float* W      = (const float*)d_in[1];
    const float* C      = (const float*)d_in[2];
    const float* bias   = (const float*)d_in[3];
    float* out = (float*)d_out;
    char* ws   = (char*)d_ws;

    double*         M64    = (double*)(ws + WS_M64_B);
    unsigned short* Mh     = (unsigned short*)(ws + WS_MH_B);
    unsigned short* Ml     = (unsigned short*)(ws + WS_ML_B);
    double*         sumP   = (double*)(ws + WS_SUMP_B);
    float*          counts = (float*)(ws + WS_CNT_B);
    int*            nmarg  = (int*)(ws + WS_NMARG_B);
    int*            list   = (int*)(ws + WS_LIST_B);

    // zero sumP + counts + nmarg (contiguous)
    hipMemsetAsync(ws + WS_SUMP_B, 0, NUM_EXPERTS * 8 + NUM_EXPERTS * 4 + 16, stream);

    cw_gemm_f64<<<dim3(D_MODEL / 64, NUM_EXPERTS / 32), 256, 0, stream>>>(C, W, M64, Mh, Ml);

    affinity_mfma<<<dim3(T_TOKENS / 64), 256, 0, stream>>>(hidden, Mh, Ml, out + OUT_AFF, sumP);

    topk_margin<<<dim3(T_TOKENS / 4), 256, 0, stream>>>(
        out + OUT_AFF, bias, out + OUT_IDX, out + OUT_W, counts, nmarg, list);

    recheck_kernel<<<dim3(512), 256, 0, stream>>>(
        hidden, M64, bias, list, nmarg, out + OUT_IDX, out + OUT_W, counts);

    loss_f64<<<dim3(1), 256, 0, stream>>>(sumP, counts, out + OUT_LOSS);
}

// Round 4
// 585.300 us; speedup vs baseline: 1.9954x; 1.9954x over previous
//
#include <hip/hip_runtime.h>
#include <math.h>

#define T_TOKENS    16384
#define D_MODEL     2048
#define NUM_EXPERTS 256
#define TOP_K       8
#define MARGIN      6e-5f

// d_out layout (floats): idx | weights | affinities | loss
#define OUT_IDX  0
#define OUT_W    (T_TOKENS * TOP_K)
#define OUT_AFF  (2 * T_TOKENS * TOP_K)
#define OUT_LOSS (2 * T_TOKENS * TOP_K + T_TOKENS * NUM_EXPERTS)

// ws layout (bytes)
#define WS_M64_B   ((size_t)0)                                    // double[256*2048] 4MB
#define WS_MH_B    (WS_M64_B + (size_t)NUM_EXPERTS * D_MODEL * 8) // bf16 1MB
#define WS_ML_B    (WS_MH_B  + (size_t)NUM_EXPERTS * D_MODEL * 2) // bf16 1MB
#define WS_SUMP_B  (WS_ML_B  + (size_t)NUM_EXPERTS * D_MODEL * 2) // double[256]
#define WS_CNT_B   (WS_SUMP_B + NUM_EXPERTS * 8)                  // float[256]
#define WS_NMARG_B (WS_CNT_B  + NUM_EXPERTS * 4)                  // int (+pad)
#define WS_LIST_B  (WS_NMARG_B + 16)                              // int[16384]
#define WS_NCAND_B (WS_LIST_B + (size_t)T_TOKENS * 4)             // int[16384]
#define WS_CAND_B  (WS_NCAND_B + (size_t)T_TOKENS * 4)            // int[16384*64] 4MB

typedef __attribute__((ext_vector_type(8))) short short8;
typedef __attribute__((ext_vector_type(4))) float f32x4;

__device__ __forceinline__ unsigned short bf16_rne(float x) {
    unsigned u = __float_as_uint(x);
    u += 0x7FFFu + ((u >> 16) & 1u);
    return (unsigned short)(u >> 16);
}
__device__ __forceinline__ float bf16_f32(unsigned short h) {
    return __uint_as_float(((unsigned)h) << 16);
}

// ---------------------------------------------------------------------------
// Kernel A: M = C @ W, f64 accumulate (f32 LDS staging, inputs f32-exact).
// Outputs M64 (recheck) + bf16 split Mh/Ml (MFMA fast path).
// ---------------------------------------------------------------------------
__global__ __launch_bounds__(256) void cw_gemm_f64(
    const float* __restrict__ C, const float* __restrict__ W,
    double* __restrict__ M64, unsigned short* __restrict__ Mh,
    unsigned short* __restrict__ Ml)
{
    __shared__ float Cs[32][34];  // [d][e], even pad for b64 merge
    __shared__ float Ws[32][68];  // [d][k]

    const int tid = threadIdx.x;
    const int tx = tid & 15;
    const int ty = tid >> 4;
    const int e0 = blockIdx.y * 32;
    const int k0 = blockIdx.x * 64;

    double acc[2][4] = {{0,0,0,0},{0,0,0,0}};

    for (int d0 = 0; d0 < D_MODEL; d0 += 32) {
        {
            const int e = tid >> 3, d4 = (tid & 7) * 4;
            const float4 v = *(const float4*)(C + (size_t)(e0 + e) * D_MODEL + d0 + d4);
            Cs[d4 + 0][e] = v.x; Cs[d4 + 1][e] = v.y;
            Cs[d4 + 2][e] = v.z; Cs[d4 + 3][e] = v.w;
        }
        #pragma unroll
        for (int r = 0; r < 2; ++r) {
            const int idx = tid + r * 256;
            const int d = idx >> 4, k4 = (idx & 15) * 4;
            *(float4*)&Ws[d][k4] =
                *(const float4*)(W + (size_t)(d0 + d) * D_MODEL + k0 + k4);
        }
        __syncthreads();
        #pragma unroll
        for (int dd = 0; dd < 32; ++dd) {
            const float2 a2 = *(const float2*)&Cs[dd][ty * 2];
            const double a0 = (double)a2.x, a1 = (double)a2.y;
            const float4 b4 = *(const float4*)&Ws[dd][tx * 4];
            const double b[4] = {(double)b4.x, (double)b4.y, (double)b4.z, (double)b4.w};
            #pragma unroll
            for (int j = 0; j < 4; ++j) { acc[0][j] += a0 * b[j]; acc[1][j] += a1 * b[j]; }
        }
        __syncthreads();
    }
    #pragma unroll
    for (int i = 0; i < 2; ++i) {
        const int e = e0 + ty * 2 + i;
        #pragma unroll
        for (int j = 0; j < 4; ++j) {
            const size_t idx = (size_t)e * D_MODEL + k0 + tx * 4 + j;
            const double v = acc[i][j];
            M64[idx] = v;
            const float f = (float)v;
            const unsigned short hi = bf16_rne(f);
            const unsigned short lo = bf16_rne(f - bf16_f32(hi));
            Mh[idx] = hi; Ml[idx] = lo;
        }
    }
}

// ---------------------------------------------------------------------------
// Kernel B: fast-path affinities via bf16-split MFMA (hh + hl + lh, f32 acc).
// tile 64t x 256e, BK=32, grid 256 blocks, 4 waves.
// ---------------------------------------------------------------------------
__global__ __launch_bounds__(256) void affinity_mfma(
    const float* __restrict__ H, const unsigned short* __restrict__ Mh,
    const unsigned short* __restrict__ Ml,
    float* __restrict__ aff, double* __restrict__ sumP)
{
    __shared__ unsigned short sHh[64][40], sHl[64][40];
    __shared__ unsigned short sMh[256][40], sMl[256][40];

    const int tid = threadIdx.x;
    const int lane = tid & 63, wv = tid >> 6;
    const int m = lane & 15, quad = lane >> 4;
    const int t0 = blockIdx.x * 64;

    const int srow = tid >> 2;
    const int kq4 = (tid & 3) * 4;
    const int me = tid >> 2;
    const int mk8 = (tid & 3) * 8;

    f32x4 acc[4][4];
    #pragma unroll
    for (int i = 0; i < 4; ++i)
        #pragma unroll
        for (int j = 0; j < 4; ++j) acc[i][j] = (f32x4){0.f, 0.f, 0.f, 0.f};

    for (int kc = 0; kc < 64; ++kc) {
        const int k0 = kc * 32;
        #pragma unroll
        for (int c = 0; c < 2; ++c) {
            const float4 v = *(const float4*)(H + (size_t)(t0 + srow) * D_MODEL + k0 + kq4 + c * 16);
            unsigned short h0 = bf16_rne(v.x), h1 = bf16_rne(v.y),
                           h2 = bf16_rne(v.z), h3 = bf16_rne(v.w);
            unsigned short l0 = bf16_rne(v.x - bf16_f32(h0)),
                           l1 = bf16_rne(v.y - bf16_f32(h1)),
                           l2 = bf16_rne(v.z - bf16_f32(h2)),
                           l3 = bf16_rne(v.w - bf16_f32(h3));
            uint2 ph, pl;
            ph.x = (unsigned)h0 | ((unsigned)h1 << 16); ph.y = (unsigned)h2 | ((unsigned)h3 << 16);
            pl.x = (unsigned)l0 | ((unsigned)l1 << 16); pl.y = (unsigned)l2 | ((unsigned)l3 << 16);
            *(uint2*)&sHh[srow][kq4 + c * 16] = ph;
            *(uint2*)&sHl[srow][kq4 + c * 16] = pl;
        }
        #pragma unroll
        for (int p = 0; p < 4; ++p) {
            const int e = p * 64 + me;
            const size_t g = (size_t)e * D_MODEL + k0 + mk8;
            *(uint4*)&sMh[e][mk8] = *(const uint4*)(Mh + g);
            *(uint4*)&sMl[e][mk8] = *(const uint4*)(Ml + g);
        }
        __syncthreads();

        short8 ah[4], al[4], bh[4], bl[4];
        #pragma unroll
        for (int i = 0; i < 4; ++i) {
            ah[i] = *(const short8*)&sHh[i * 16 + m][quad * 8];
            al[i] = *(const short8*)&sHl[i * 16 + m][quad * 8];
        }
        #pragma unroll
        for (int j = 0; j < 4; ++j) {
            bh[j] = *(const short8*)&sMh[wv * 64 + j * 16 + m][quad * 8];
            bl[j] = *(const short8*)&sMl[wv * 64 + j * 16 + m][quad * 8];
        }
        #pragma unroll
        for (int i = 0; i < 4; ++i)
            #pragma unroll
            for (int j = 0; j < 4; ++j) {
                acc[i][j] = __builtin_amdgcn_mfma_f32_16x16x32_bf16(ah[i], bh[j], acc[i][j], 0, 0, 0);
                acc[i][j] = __builtin_amdgcn_mfma_f32_16x16x32_bf16(ah[i], bl[j], acc[i][j], 0, 0, 0);
                acc[i][j] = __builtin_amdgcn_mfma_f32_16x16x32_bf16(al[i], bh[j], acc[i][j], 0, 0, 0);
            }
        __syncthreads();
    }

    #pragma unroll
    for (int j = 0; j < 4; ++j) {
        const int e = wv * 64 + j * 16 + m;
        float colsum = 0.f;
        #pragma unroll
        for (int i = 0; i < 4; ++i) {
            const int tbase = t0 + i * 16 + quad * 4;
            #pragma unroll
            for (int r = 0; r < 4; ++r) {
                const float v = acc[i][j][r];
                aff[(size_t)(tbase + r) * NUM_EXPERTS + e] = v;
                colsum += 1.f / (1.f + expf(-v));
            }
        }
        colsum += __shfl_xor(colsum, 16, 64);
        colsum += __shfl_xor(colsum, 32, 64);
        if (quad == 0) atomicAdd(&sumP[e], (double)colsum);
    }
}

// ---------------------------------------------------------------------------
// Kernel C: fast top-9 (f32) with margin test. Non-marginal: write outputs.
// Marginal: emit token + candidate set {e : s_e >= s8 - MARGIN}.
// ---------------------------------------------------------------------------
__global__ __launch_bounds__(256) void topk_margin(
    const float* __restrict__ aff, const float* __restrict__ bias,
    float* __restrict__ out_idx, float* __restrict__ out_w,
    float* __restrict__ counts, int* __restrict__ nmarg,
    int* __restrict__ list, int* __restrict__ ncand, int* __restrict__ cand)
{
    const int lane = threadIdx.x & 63;
    const int wv = threadIdx.x >> 6;
    const int t = blockIdx.x * 4 + wv;

    const float4 av = *(const float4*)(aff + (size_t)t * NUM_EXPERTS + lane * 4);
    const float4 bv = *(const float4*)(bias + lane * 4);
    float g[4], s[4], s0[4];
    g[0] = 1.f / (1.f + expf(-av.x)); s[0] = s0[0] = g[0] + bv.x;
    g[1] = 1.f / (1.f + expf(-av.y)); s[1] = s0[1] = g[1] + bv.y;
    g[2] = 1.f / (1.f + expf(-av.z)); s[2] = s0[2] = g[2] + bv.z;
    g[3] = 1.f / (1.f + expf(-av.w)); s[3] = s0[3] = g[3] + bv.w;

    float wsum = 0.f, my_g = 0.f, prev = 0.f, minGap = 1e30f, s8 = 0.f;
    int my_i = 0;

    for (int it = 0; it < 9; ++it) {
        float bs = s[0], bg = g[0]; int bi = lane * 4;
        #pragma unroll
        for (int j = 1; j < 4; ++j)
            if (s[j] > bs) { bs = s[j]; bg = g[j]; bi = lane * 4 + j; }
        #pragma unroll
        for (int off = 1; off < 64; off <<= 1) {
            const float os = __shfl_xor(bs, off, 64);
            const float og = __shfl_xor(bg, off, 64);
            const int   oi = __shfl_xor(bi, off, 64);
            if (os > bs || (os == bs && oi < bi)) { bs = os; bg = og; bi = oi; }
        }
        if (it < TOP_K) {
            wsum += bg;
            if (lane == it) { my_i = bi; my_g = bg; }
            if (it == 7) s8 = bs;
        }
        if (it > 0) minGap = fminf(minGap, prev - bs);
        prev = bs;
        if ((bi >> 2) == lane) s[bi & 3] = -1e30f;
    }

    if (minGap < MARGIN) {
        int pos = 0;
        if (lane == 0) pos = atomicAdd(nmarg, 1);
        pos = __shfl(pos, 0, 64);
        const float thresh = s8 - MARGIN;
        int base = 0;
        #pragma unroll
        for (int j = 0; j < 4; ++j) {
            const bool c = (s0[j] >= thresh);
            const unsigned long long mk = __ballot(c);
            const int mypos = base + __popcll(mk & ((1ull << lane) - 1ull));
            if (c && mypos < 64) cand[(size_t)pos * 64 + mypos] = lane * 4 + j;
            base += (int)__popcll(mk);
        }
        if (lane == 0) { list[pos] = t; ncand[pos] = min(base, 64); }
    } else {
        const float inv = 1.f / (wsum + 1e-10f);
        if (lane < TOP_K) {
            out_idx[(size_t)t * TOP_K + lane] = (float)my_i;
            out_w[(size_t)t * TOP_K + lane] = my_g * inv;
            atomicAdd(&counts[my_i], 1.0f);
        }
    }
}

// ---------------------------------------------------------------------------
// Kernel R: candidate-set f64 recheck. One block (4 waves) per marginal
// token; wave-per-candidate f64 dot, then single-wave f64 top-8.
// ---------------------------------------------------------------------------
__global__ __launch_bounds__(256) void recheck2(
    const float* __restrict__ H, const double* __restrict__ M64,
    const float* __restrict__ bias, const int* __restrict__ list,
    const int* __restrict__ ncand, const int* __restrict__ cand,
    const int* __restrict__ nmarg, float* __restrict__ out_idx,
    float* __restrict__ out_w, float* __restrict__ counts)
{
    __shared__ float hsf[D_MODEL];      // 8 KiB
    __shared__ double sg[64], ssc[64];  // 1 KiB

    const int n = *nmarg;
    const int lane = threadIdx.x & 63, wv = threadIdx.x >> 6;

    for (int i = (int)blockIdx.x; i < n; i += (int)gridDim.x) {
        const int t = list[i];
        const int nc = ncand[i];

        for (int q = threadIdx.x; q < D_MODEL / 4; q += 256)
            *(float4*)&hsf[q * 4] = *(const float4*)(H + (size_t)t * D_MODEL + q * 4);
        __syncthreads();

        for (int c = wv; c < nc; c += 4) {
            const int e = cand[(size_t)i * 64 + c];
            const double* mrow = M64 + (size_t)e * D_MODEL;
            double acc = 0.0;
            #pragma unroll 8
            for (int j = 0; j < 32; ++j) {
                const int k = lane + 64 * j;
                acc = fma((double)hsf[k], mrow[k], acc);
            }
            #pragma unroll
            for (int off = 1; off < 64; off <<= 1) acc += __shfl_xor(acc, off, 64);
            if (lane == 0) {
                const double gg = 1.0 / (1.0 + exp(-acc));
                sg[c] = gg;
                ssc[c] = gg + (double)bias[e];
            }
        }
        __syncthreads();

        if (wv == 0) {
            double s = -1e300, g = 0.0;
            int id = 1 << 20;
            if (lane < nc) { s = ssc[lane]; g = sg[lane]; id = cand[(size_t)i * 64 + lane]; }

            double wsum = 0.0, my_g = 0.0;
            int my_i = 0;
            for (int it = 0; it < TOP_K; ++it) {
                double bs = s, bg = g; int bi = id;
                #pragma unroll
                for (int off = 1; off < 64; off <<= 1) {
                    const double os = __shfl_xor(bs, off, 64);
                    const double og = __shfl_xor(bg, off, 64);
                    const int    oi = __shfl_xor(bi, off, 64);
                    if (os > bs || (os == bs && oi < bi)) { bs = os; bg = og; bi = oi; }
                }
                wsum += bg;
                if (lane == it) { my_i = bi; my_g = bg; }
                if (id == bi) s = -1e300;
            }
            const double inv = 1.0 / (wsum + 1e-10);
            if (lane < TOP_K) {
                out_idx[(size_t)t * TOP_K + lane] = (float)my_i;
                out_w[(size_t)t * TOP_K + lane] = (float)(my_g * inv);
                atomicAdd(&counts[my_i], 1.0f);
            }
        }
        __syncthreads();
    }
}

// ---------------------------------------------------------------------------
// Kernel D: balance loss
// ---------------------------------------------------------------------------
__global__ __launch_bounds__(256) void loss_f64(
    const double* __restrict__ sumP, const float* __restrict__ counts,
    float* __restrict__ out_loss)
{
    __shared__ double red[256];
    const int e = threadIdx.x;
    red[e] = (double)counts[e] * sumP[e];
    __syncthreads();
    #pragma unroll
    for (int sft = 128; sft > 0; sft >>= 1) {
        if (e < sft) red[e] += red[e + sft];
        __syncthreads();
    }
    if (e == 0) {
        const double denom = (double)T_TOKENS * (double)TOP_K * (double)T_TOKENS;
        out_loss[0] = (float)(0.001 * ((double)NUM_EXPERTS / (double)TOP_K) * red[0] / denom);
    }
}

extern "C" void kernel_launch(void* const* d_in, const int* in_sizes, int n_in,
                              void* d_out, int out_size, void* d_ws, size_t ws_size,
                              hipStream_t stream) {
    (void)in_sizes; (void)n_in; (void)out_size; (void)ws_size;
    const float* hidden = (const float*)d_in[0];
    const float* W      = (const float*)d_in[1];
    const float* C      = (const float*)d_in[2];
    const float* bias   = (const float*)d_in[3];
    float* out = (float*)d_out;
    char* ws   = (char*)d_ws;

    double*         M64    = (double*)(ws + WS_M64_B);
    unsigned short* Mh     = (unsigned short*)(ws + WS_MH_B);
    unsigned short* Ml     = (unsigned short*)(ws + WS_ML_B);
    double*         sumP   = (double*)(ws + WS_SUMP_B);
    float*          counts = (float*)(ws + WS_CNT_B);
    int*            nmarg  = (int*)(ws + WS_NMARG_B);
    int*            list   = (int*)(ws + WS_LIST_B);
    int*            ncand  = (int*)(ws + WS_NCAND_B);
    int*            cand   = (int*)(ws + WS_CAND_B);

    hipMemsetAsync(ws + WS_SUMP_B, 0, NUM_EXPERTS * 8 + NUM_EXPERTS * 4 + 16, stream);

    cw_gemm_f64<<<dim3(D_MODEL / 64, NUM_EXPERTS / 32), 256, 0, stream>>>(C, W, M64, Mh, Ml);

    affinity_mfma<<<dim3(T_TOKENS / 64), 256, 0, stream>>>(hidden, Mh, Ml, out + OUT_AFF, sumP);

    topk_margin<<<dim3(T_TOKENS / 4), 256, 0, stream>>>(
        out + OUT_AFF, bias, out + OUT_IDX, out + OUT_W, counts, nmarg, list, ncand, cand);

    recheck2<<<dim3(2048), 256, 0, stream>>>(
        hidden, M64, bias, list, ncand, cand, nmarg, out + OUT_IDX, out + OUT_W, counts);

    loss_f64<<<dim3(1), 256, 0, stream>>>(sumP, counts, out + OUT_LOSS);
}

// Round 5
// 558.311 us; speedup vs baseline: 2.0918x; 1.0483x over previous
//
#include <hip/hip_runtime.h>
#include <math.h>

#define T_TOKENS    16384
#define D_MODEL     2048
#define NUM_EXPERTS 256
#define TOP_K       8
#define MARGIN      6e-5f

// d_out layout (floats): idx | weights | affinities | loss
#define OUT_IDX  0
#define OUT_W    (T_TOKENS * TOP_K)
#define OUT_AFF  (2 * T_TOKENS * TOP_K)
#define OUT_LOSS (2 * T_TOKENS * TOP_K + T_TOKENS * NUM_EXPERTS)

// ws layout (bytes)
#define WS_M64_B   ((size_t)0)                                    // double[256*2048] 4MB
#define WS_MH_B    (WS_M64_B + (size_t)NUM_EXPERTS * D_MODEL * 8) // bf16 1MB
#define WS_ML_B    (WS_MH_B  + (size_t)NUM_EXPERTS * D_MODEL * 2) // bf16 1MB
#define WS_SUMP_B  (WS_ML_B  + (size_t)NUM_EXPERTS * D_MODEL * 2) // double[256]
#define WS_CNT_B   (WS_SUMP_B + NUM_EXPERTS * 8)                  // int[256]
#define WS_NMARG_B (WS_CNT_B  + NUM_EXPERTS * 4)                  // int (+pad)
#define WS_LIST_B  (WS_NMARG_B + 16)                              // int[16384]
#define WS_NCAND_B (WS_LIST_B + (size_t)T_TOKENS * 4)             // int[16384]
#define WS_CAND_B  (WS_NCAND_B + (size_t)T_TOKENS * 4)            // int[16384*64] 4MB
#define WS_CSP_B   (WS_CAND_B + (size_t)T_TOKENS * 64 * 4)        // float[256*256] 256KB

typedef __attribute__((ext_vector_type(8))) short short8;
typedef __attribute__((ext_vector_type(4))) float f32x4;

__device__ __forceinline__ unsigned short bf16_rne(float x) {
    unsigned u = __float_as_uint(x);
    u += 0x7FFFu + ((u >> 16) & 1u);
    return (unsigned short)(u >> 16);
}
__device__ __forceinline__ float bf16_f32(unsigned short h) {
    return __uint_as_float(((unsigned)h) << 16);
}
// monotonic float -> uint order map (increasing)
__device__ __forceinline__ unsigned ford(float f) {
    unsigned u = __float_as_uint(f);
    return ((int)u >= 0) ? (u | 0x80000000u) : ~u;
}
__device__ __forceinline__ float finv(unsigned o) {
    return (o & 0x80000000u) ? __uint_as_float(o ^ 0x80000000u)
                             : __uint_as_float(~o);
}

// ---------------------------------------------------------------------------
// Kernel A: M = C @ W, f64 accumulate. Outputs M64 + bf16 split Mh/Ml.
// ---------------------------------------------------------------------------
__global__ __launch_bounds__(256) void cw_gemm_f64(
    const float* __restrict__ C, const float* __restrict__ W,
    double* __restrict__ M64, unsigned short* __restrict__ Mh,
    unsigned short* __restrict__ Ml)
{
    __shared__ float Cs[32][34];
    __shared__ float Ws[32][68];

    const int tid = threadIdx.x;
    const int tx = tid & 15;
    const int ty = tid >> 4;
    const int e0 = blockIdx.y * 32;
    const int k0 = blockIdx.x * 64;

    double acc[2][4] = {{0,0,0,0},{0,0,0,0}};

    for (int d0 = 0; d0 < D_MODEL; d0 += 32) {
        {
            const int e = tid >> 3, d4 = (tid & 7) * 4;
            const float4 v = *(const float4*)(C + (size_t)(e0 + e) * D_MODEL + d0 + d4);
            Cs[d4 + 0][e] = v.x; Cs[d4 + 1][e] = v.y;
            Cs[d4 + 2][e] = v.z; Cs[d4 + 3][e] = v.w;
        }
        #pragma unroll
        for (int r = 0; r < 2; ++r) {
            const int idx = tid + r * 256;
            const int d = idx >> 4, k4 = (idx & 15) * 4;
            *(float4*)&Ws[d][k4] =
                *(const float4*)(W + (size_t)(d0 + d) * D_MODEL + k0 + k4);
        }
        __syncthreads();
        #pragma unroll
        for (int dd = 0; dd < 32; ++dd) {
            const float2 a2 = *(const float2*)&Cs[dd][ty * 2];
            const double a0 = (double)a2.x, a1 = (double)a2.y;
            const float4 b4 = *(const float4*)&Ws[dd][tx * 4];
            const double b[4] = {(double)b4.x, (double)b4.y, (double)b4.z, (double)b4.w};
            #pragma unroll
            for (int j = 0; j < 4; ++j) { acc[0][j] += a0 * b[j]; acc[1][j] += a1 * b[j]; }
        }
        __syncthreads();
    }
    #pragma unroll
    for (int i = 0; i < 2; ++i) {
        const int e = e0 + ty * 2 + i;
        #pragma unroll
        for (int j = 0; j < 4; ++j) {
            const size_t idx = (size_t)e * D_MODEL + k0 + tx * 4 + j;
            const double v = acc[i][j];
            M64[idx] = v;
            const float f = (float)v;
            const unsigned short hi = bf16_rne(f);
            const unsigned short lo = bf16_rne(f - bf16_f32(hi));
            Mh[idx] = hi; Ml[idx] = lo;
        }
    }
}

// ---------------------------------------------------------------------------
// Kernel B: affinities via bf16-split MFMA (hh + hl + lh, f32 acc) with a
// register-prefetch pipeline. Per-block sigmoid column sums -> colsumPart
// (NO atomics). tile 64t x 256e, BK=32, grid 256, 4 waves.
// ---------------------------------------------------------------------------
__global__ __launch_bounds__(256, 1) void affinity_mfma(
    const float* __restrict__ H, const unsigned short* __restrict__ Mh,
    const unsigned short* __restrict__ Ml,
    float* __restrict__ aff, float* __restrict__ colsumPart)
{
    __shared__ unsigned short sHh[64][40], sHl[64][40];
    __shared__ unsigned short sMh[256][40], sMl[256][40];

    const int tid = threadIdx.x;
    const int lane = tid & 63, wv = tid >> 6;
    const int m = lane & 15, quad = lane >> 4;
    const int t0 = blockIdx.x * 64;

    const int srow = tid >> 2;
    const int kq4 = (tid & 3) * 4;
    const int me = tid >> 2;
    const int mk8 = (tid & 3) * 8;

    f32x4 acc[4][4];
    #pragma unroll
    for (int i = 0; i < 4; ++i)
        #pragma unroll
        for (int j = 0; j < 4; ++j) acc[i][j] = (f32x4){0.f, 0.f, 0.f, 0.f};

    float4 hA0, hB0, hA1, hB1;
    uint4 mh0[4], ml0[4], mh1[4], ml1[4];

    auto loadT = [&](int kc, float4& ha, float4& hb, uint4* mh, uint4* ml) {
        const int k0 = kc * 32;
        const float* hp = H + (size_t)(t0 + srow) * D_MODEL + k0 + kq4;
        ha = *(const float4*)hp;
        hb = *(const float4*)(hp + 16);
        #pragma unroll
        for (int p = 0; p < 4; ++p) {
            const size_t g = (size_t)(p * 64 + me) * D_MODEL + k0 + mk8;
            mh[p] = *(const uint4*)(Mh + g);
            ml[p] = *(const uint4*)(Ml + g);
        }
    };
    auto stageT = [&](const float4& ha, const float4& hb, const uint4* mh, const uint4* ml) {
        #pragma unroll
        for (int c = 0; c < 2; ++c) {
            const float4 v = c ? hb : ha;
            unsigned short h0 = bf16_rne(v.x), h1 = bf16_rne(v.y),
                           h2 = bf16_rne(v.z), h3 = bf16_rne(v.w);
            unsigned short l0 = bf16_rne(v.x - bf16_f32(h0)),
                           l1 = bf16_rne(v.y - bf16_f32(h1)),
                           l2 = bf16_rne(v.z - bf16_f32(h2)),
                           l3 = bf16_rne(v.w - bf16_f32(h3));
            uint2 ph, pl;
            ph.x = (unsigned)h0 | ((unsigned)h1 << 16); ph.y = (unsigned)h2 | ((unsigned)h3 << 16);
            pl.x = (unsigned)l0 | ((unsigned)l1 << 16); pl.y = (unsigned)l2 | ((unsigned)l3 << 16);
            *(uint2*)&sHh[srow][kq4 + c * 16] = ph;
            *(uint2*)&sHl[srow][kq4 + c * 16] = pl;
        }
        #pragma unroll
        for (int p = 0; p < 4; ++p) {
            *(uint4*)&sMh[p * 64 + me][mk8] = mh[p];
            *(uint4*)&sMl[p * 64 + me][mk8] = ml[p];
        }
    };
    auto mfmaT = [&]() {
        short8 ah[4], al[4], bh[4], bl[4];
        #pragma unroll
        for (int i = 0; i < 4; ++i) {
            ah[i] = *(const short8*)&sHh[i * 16 + m][quad * 8];
            al[i] = *(const short8*)&sHl[i * 16 + m][quad * 8];
        }
        #pragma unroll
        for (int j = 0; j < 4; ++j) {
            bh[j] = *(const short8*)&sMh[wv * 64 + j * 16 + m][quad * 8];
            bl[j] = *(const short8*)&sMl[wv * 64 + j * 16 + m][quad * 8];
        }
        #pragma unroll
        for (int i = 0; i < 4; ++i)
            #pragma unroll
            for (int j = 0; j < 4; ++j) {
                acc[i][j] = __builtin_amdgcn_mfma_f32_16x16x32_bf16(ah[i], bh[j], acc[i][j], 0, 0, 0);
                acc[i][j] = __builtin_amdgcn_mfma_f32_16x16x32_bf16(ah[i], bl[j], acc[i][j], 0, 0, 0);
                acc[i][j] = __builtin_amdgcn_mfma_f32_16x16x32_bf16(al[i], bh[j], acc[i][j], 0, 0, 0);
            }
    };

    loadT(0, hA0, hB0, mh0, ml0);
    for (int kc = 0; kc < 64; kc += 2) {
        stageT(hA0, hB0, mh0, ml0);
        loadT(kc + 1, hA1, hB1, mh1, ml1);       // in flight across MFMA below
        __syncthreads();
        mfmaT();
        __syncthreads();
        stageT(hA1, hB1, mh1, ml1);
        if (kc + 2 < 64) loadT(kc + 2, hA0, hB0, mh0, ml0);
        __syncthreads();
        mfmaT();
        __syncthreads();
    }

    #pragma unroll
    for (int j = 0; j < 4; ++j) {
        const int e = wv * 64 + j * 16 + m;
        float colsum = 0.f;
        #pragma unroll
        for (int i = 0; i < 4; ++i) {
            const int tbase = t0 + i * 16 + quad * 4;
            #pragma unroll
            for (int r = 0; r < 4; ++r) {
                const float v = acc[i][j][r];
                aff[(size_t)(tbase + r) * NUM_EXPERTS + e] = v;
                colsum += 1.f / (1.f + expf(-v));
            }
        }
        colsum += __shfl_xor(colsum, 16, 64);
        colsum += __shfl_xor(colsum, 32, 64);
        if (quad == 0) colsumPart[(size_t)blockIdx.x * NUM_EXPERTS + e] = colsum;
    }
}

// ---------------------------------------------------------------------------
// Kernel C: fast top-9 (f32) on packed u64 keys + margin test. NO count
// atomics. Marginal tokens emit candidate sets.
// ---------------------------------------------------------------------------
__global__ __launch_bounds__(256) void topk_margin(
    const float* __restrict__ aff, const float* __restrict__ bias,
    float* __restrict__ out_idx, float* __restrict__ out_w,
    int* __restrict__ nmarg, int* __restrict__ list,
    int* __restrict__ ncand, int* __restrict__ cand)
{
    const int lane = threadIdx.x & 63;
    const int wv = threadIdx.x >> 6;
    const int t = blockIdx.x * 4 + wv;

    const float4 av = *(const float4*)(aff + (size_t)t * NUM_EXPERTS + lane * 4);
    const float4 bv = *(const float4*)(bias + lane * 4);
    float g[4], s0[4];
    g[0] = 1.f / (1.f + expf(-av.x)); s0[0] = g[0] + bv.x;
    g[1] = 1.f / (1.f + expf(-av.y)); s0[1] = g[1] + bv.y;
    g[2] = 1.f / (1.f + expf(-av.z)); s0[2] = g[2] + bv.z;
    g[3] = 1.f / (1.f + expf(-av.w)); s0[3] = g[3] + bv.w;

    unsigned long long kw[4];
    #pragma unroll
    for (int j = 0; j < 4; ++j)
        kw[j] = ((unsigned long long)ford(s0[j]) << 32)
              | (unsigned long long)(0xFFFFFFFFu - (unsigned)(lane * 4 + j));

    float wsum = 0.f, my_g = 0.f, prevs = 0.f, minGap = 1e30f, s8 = 0.f;
    int my_i = 0;

    #pragma unroll
    for (int it = 0; it < 9; ++it) {
        unsigned long long bk = kw[0];
        if (kw[1] > bk) bk = kw[1];
        if (kw[2] > bk) bk = kw[2];
        if (kw[3] > bk) bk = kw[3];
        #pragma unroll
        for (int off = 1; off < 64; off <<= 1) {
            const unsigned long long ok = __shfl_xor(bk, off, 64);
            if (ok > bk) bk = ok;
        }
        const unsigned o = (unsigned)(bk >> 32);
        const float sv = finv(o);
        const int e = (int)(0xFFFFFFFFu - (unsigned)(bk & 0xFFFFFFFFu));
        const int ej = e & 3, el = e >> 2;
        const float gl = (ej == 0) ? g[0] : (ej == 1) ? g[1] : (ej == 2) ? g[2] : g[3];
        const float gv = __shfl(gl, el, 64);
        if (it < TOP_K) {
            wsum += gv;
            if (lane == it) { my_i = e; my_g = gv; }
            if (it == 7) s8 = sv;
        }
        if (it > 0) minGap = fminf(minGap, prevs - sv);
        prevs = sv;
        if (lane == el) {
            if (ej == 0) kw[0] = 0ull; else if (ej == 1) kw[1] = 0ull;
            else if (ej == 2) kw[2] = 0ull; else kw[3] = 0ull;
        }
    }

    if (minGap < MARGIN) {
        int pos = 0;
        if (lane == 0) pos = atomicAdd(nmarg, 1);
        pos = __shfl(pos, 0, 64);
        const float thresh = s8 - MARGIN;
        int base = 0;
        #pragma unroll
        for (int j = 0; j < 4; ++j) {
            const bool c = (s0[j] >= thresh);
            const unsigned long long mk = __ballot(c);
            const int mypos = base + __popcll(mk & ((1ull << lane) - 1ull));
            if (c && mypos < 64) cand[(size_t)pos * 64 + mypos] = lane * 4 + j;
            base += (int)__popcll(mk);
        }
        if (lane == 0) { list[pos] = t; ncand[pos] = min(base, 64); }
    } else {
        const float inv = 1.f / (wsum + 1e-10f);
        if (lane < TOP_K) {
            out_idx[(size_t)t * TOP_K + lane] = (float)my_i;
            out_w[(size_t)t * TOP_K + lane] = my_g * inv;
        }
    }
}

// ---------------------------------------------------------------------------
// Kernel R: candidate-set f64 recheck (no count atomics).
// ---------------------------------------------------------------------------
__global__ __launch_bounds__(256) void recheck2(
    const float* __restrict__ H, const double* __restrict__ M64,
    const float* __restrict__ bias, const int* __restrict__ list,
    const int* __restrict__ ncand, const int* __restrict__ cand,
    const int* __restrict__ nmarg, float* __restrict__ out_idx,
    float* __restrict__ out_w)
{
    __shared__ float hsf[D_MODEL];
    __shared__ double sg[64], ssc[64];

    const int n = *nmarg;
    const int lane = threadIdx.x & 63, wv = threadIdx.x >> 6;

    for (int i = (int)blockIdx.x; i < n; i += (int)gridDim.x) {
        const int t = list[i];
        const int nc = ncand[i];

        for (int q = threadIdx.x; q < D_MODEL / 4; q += 256)
            *(float4*)&hsf[q * 4] = *(const float4*)(H + (size_t)t * D_MODEL + q * 4);
        __syncthreads();

        for (int c = wv; c < nc; c += 4) {
            const int e = cand[(size_t)i * 64 + c];
            const double* mrow = M64 + (size_t)e * D_MODEL;
            double acc = 0.0;
            #pragma unroll 8
            for (int j = 0; j < 32; ++j) {
                const int k = lane + 64 * j;
                acc = fma((double)hsf[k], mrow[k], acc);
            }
            #pragma unroll
            for (int off = 1; off < 64; off <<= 1) acc += __shfl_xor(acc, off, 64);
            if (lane == 0) {
                const double gg = 1.0 / (1.0 + exp(-acc));
                sg[c] = gg;
                ssc[c] = gg + (double)bias[e];
            }
        }
        __syncthreads();

        if (wv == 0) {
            double s = -1e300, g = 0.0;
            int id = 1 << 20;
            if (lane < nc) { s = ssc[lane]; g = sg[lane]; id = cand[(size_t)i * 64 + lane]; }

            double wsum = 0.0, my_g = 0.0;
            int my_i = 0;
            for (int it = 0; it < TOP_K; ++it) {
                double bs = s, bg = g; int bi = id;
                #pragma unroll
                for (int off = 1; off < 64; off <<= 1) {
                    const double os = __shfl_xor(bs, off, 64);
                    const double og = __shfl_xor(bg, off, 64);
                    const int    oi = __shfl_xor(bi, off, 64);
                    if (os > bs || (os == bs && oi < bi)) { bs = os; bg = og; bi = oi; }
                }
                wsum += bg;
                if (lane == it) { my_i = bi; my_g = bg; }
                if (id == bi) s = -1e300;
            }
            const double inv = 1.0 / (wsum + 1e-10);
            if (lane < TOP_K) {
                out_idx[(size_t)t * TOP_K + lane] = (float)my_i;
                out_w[(size_t)t * TOP_K + lane] = (float)(my_g * inv);
            }
        }
        __syncthreads();
    }
}

// ---------------------------------------------------------------------------
// Kernel H: histogram final out_idx -> counts (int), and reduce colsumPart
// -> sumP. grid MUST be 64 blocks x 256 threads.
// ---------------------------------------------------------------------------
__global__ __launch_bounds__(256) void hist_reduce(
    const float* __restrict__ out_idx, const float* __restrict__ colsumPart,
    int* __restrict__ counts, double* __restrict__ sumP)
{
    __shared__ int h[NUM_EXPERTS];
    const int tid = threadIdx.x;
    const int lane = tid & 63, wv = tid >> 6;
    h[tid] = 0;
    __syncthreads();
    for (int i = (int)blockIdx.x * 256 + tid; i < T_TOKENS * TOP_K; i += 64 * 256)
        atomicAdd(&h[(int)out_idx[i]], 1);
    __syncthreads();
    if (h[tid] != 0) atomicAdd(&counts[tid], h[tid]);

    // sumP reduce: expert e = blockIdx.x*4 + wv
    const int e = (int)blockIdx.x * 4 + wv;
    float ps = 0.f;
    for (int p = lane; p < 256; p += 64)
        ps += colsumPart[(size_t)p * NUM_EXPERTS + e];
    #pragma unroll
    for (int off = 1; off < 64; off <<= 1) ps += __shfl_xor(ps, off, 64);
    if (lane == 0) sumP[e] = (double)ps;
}

// ---------------------------------------------------------------------------
// Kernel D: balance loss
// ---------------------------------------------------------------------------
__global__ __launch_bounds__(256) void loss_f64(
    const double* __restrict__ sumP, const int* __restrict__ counts,
    float* __restrict__ out_loss)
{
    __shared__ double red[256];
    const int e = threadIdx.x;
    red[e] = (double)counts[e] * sumP[e];
    __syncthreads();
    #pragma unroll
    for (int sft = 128; sft > 0; sft >>= 1) {
        if (e < sft) red[e] += red[e + sft];
        __syncthreads();
    }
    if (e == 0) {
        const double denom = (double)T_TOKENS * (double)TOP_K * (double)T_TOKENS;
        out_loss[0] = (float)(0.001 * ((double)NUM_EXPERTS / (double)TOP_K) * red[0] / denom);
    }
}

extern "C" void kernel_launch(void* const* d_in, const int* in_sizes, int n_in,
                              void* d_out, int out_size, void* d_ws, size_t ws_size,
                              hipStream_t stream) {
    (void)in_sizes; (void)n_in; (void)out_size; (void)ws_size;
    const float* hidden = (const float*)d_in[0];
    const float* W      = (const float*)d_in[1];
    const float* C      = (const float*)d_in[2];
    const float* bias   = (const float*)d_in[3];
    float* out = (float*)d_out;
    char* ws   = (char*)d_ws;

    double*         M64    = (double*)(ws + WS_M64_B);
    unsigned short* Mh     = (unsigned short*)(ws + WS_MH_B);
    unsigned short* Ml     = (unsigned short*)(ws + WS_ML_B);
    double*         sumP   = (double*)(ws + WS_SUMP_B);
    int*            counts = (int*)(ws + WS_CNT_B);
    int*            nmarg  = (int*)(ws + WS_NMARG_B);
    int*            list   = (int*)(ws + WS_LIST_B);
    int*            ncand  = (int*)(ws + WS_NCAND_B);
    int*            cand   = (int*)(ws + WS_CAND_B);
    float*          csp    = (float*)(ws + WS_CSP_B);

    // zero counts + nmarg (sumP is overwritten by hist_reduce)
    hipMemsetAsync(ws + WS_CNT_B, 0, NUM_EXPERTS * 4 + 16, stream);

    cw_gemm_f64<<<dim3(D_MODEL / 64, NUM_EXPERTS / 32), 256, 0, stream>>>(C, W, M64, Mh, Ml);

    affinity_mfma<<<dim3(T_TOKENS / 64), 256, 0, stream>>>(hidden, Mh, Ml, out + OUT_AFF, csp);

    topk_margin<<<dim3(T_TOKENS / 4), 256, 0, stream>>>(
        out + OUT_AFF, bias, out + OUT_IDX, out + OUT_W, nmarg, list, ncand, cand);

    recheck2<<<dim3(2048), 256, 0, stream>>>(
        hidden, M64, bias, list, ncand, cand, nmarg, out + OUT_IDX, out + OUT_W);

    hist_reduce<<<dim3(64), 256, 0, stream>>>(out + OUT_IDX, csp, counts, sumP);

    loss_f64<<<dim3(1), 256, 0, stream>>>(sumP, counts, out + OUT_LOSS);
}

// Round 6
// 412.780 us; speedup vs baseline: 2.8294x; 1.3526x over previous
//
#include <hip/hip_runtime.h>
#include <math.h>

#define T_TOKENS    16384
#define D_MODEL     2048
#define NUM_EXPERTS 256
#define TOP_K       8
#define MARGIN      6e-5f

// d_out layout (floats): idx | weights | affinities | loss
#define OUT_IDX  0
#define OUT_W    (T_TOKENS * TOP_K)
#define OUT_AFF  (2 * T_TOKENS * TOP_K)
#define OUT_LOSS (2 * T_TOKENS * TOP_K + T_TOKENS * NUM_EXPERTS)

// ws layout (bytes)
#define WS_M64_B   ((size_t)0)                                    // double[256*2048] 4MB
#define WS_MH_B    (WS_M64_B + (size_t)NUM_EXPERTS * D_MODEL * 8) // bf16 1MB
#define WS_ML_B    (WS_MH_B  + (size_t)NUM_EXPERTS * D_MODEL * 2) // bf16 1MB
#define WS_SUMP_B  (WS_ML_B  + (size_t)NUM_EXPERTS * D_MODEL * 2) // double[256]
#define WS_CNT_B   (WS_SUMP_B + NUM_EXPERTS * 8)                  // int[256]
#define WS_NMARG_B (WS_CNT_B  + NUM_EXPERTS * 4)                  // int (+pad)
#define WS_LIST_B  (WS_NMARG_B + 16)                              // int[16384]
#define WS_NCAND_B (WS_LIST_B + (size_t)T_TOKENS * 4)             // int[16384]
#define WS_CAND_B  (WS_NCAND_B + (size_t)T_TOKENS * 4)            // int[16384*64] 4MB
#define WS_CSP_B   (WS_CAND_B + (size_t)T_TOKENS * 64 * 4)        // float[2*256*128] 256KB
#define WS_MP_B    (WS_CSP_B + (size_t)2 * 256 * 128 * 4)         // double[2][256*2048] 8MB

typedef __attribute__((ext_vector_type(8))) short short8;
typedef __attribute__((ext_vector_type(4))) float f32x4;

__device__ __forceinline__ unsigned short bf16_rne(float x) {
    unsigned u = __float_as_uint(x);
    u += 0x7FFFu + ((u >> 16) & 1u);
    return (unsigned short)(u >> 16);
}
__device__ __forceinline__ float bf16_f32(unsigned short h) {
    return __uint_as_float(((unsigned)h) << 16);
}
__device__ __forceinline__ unsigned ford(float f) {
    unsigned u = __float_as_uint(f);
    return ((int)u >= 0) ? (u | 0x80000000u) : ~u;
}
__device__ __forceinline__ float finv(unsigned o) {
    return (o & 0x80000000u) ? __uint_as_float(o ^ 0x80000000u)
                             : __uint_as_float(~o);
}

// ---------------------------------------------------------------------------
// Kernel A1: partial M = C @ W over a D-half. tile 32e x 64k, grid (32,8,2)
// = 512 blocks (2 blocks/CU).
// ---------------------------------------------------------------------------
__global__ __launch_bounds__(256) void cw_gemm_part(
    const float* __restrict__ C, const float* __restrict__ W,
    double* __restrict__ Mpart)
{
    __shared__ float Cs[32][34];
    __shared__ float Ws[32][68];

    const int tid = threadIdx.x;
    const int tx = tid & 15;
    const int ty = tid >> 4;
    const int e0 = blockIdx.y * 32;
    const int k0 = blockIdx.x * 64;
    const int z  = blockIdx.z;

    double* Mp = Mpart + (size_t)z * NUM_EXPERTS * D_MODEL;
    double acc[2][4] = {{0,0,0,0},{0,0,0,0}};

    for (int d0 = z * 1024; d0 < (z + 1) * 1024; d0 += 32) {
        {
            const int e = tid >> 3, d4 = (tid & 7) * 4;
            const float4 v = *(const float4*)(C + (size_t)(e0 + e) * D_MODEL + d0 + d4);
            Cs[d4 + 0][e] = v.x; Cs[d4 + 1][e] = v.y;
            Cs[d4 + 2][e] = v.z; Cs[d4 + 3][e] = v.w;
        }
        #pragma unroll
        for (int r = 0; r < 2; ++r) {
            const int idx = tid + r * 256;
            const int d = idx >> 4, k4 = (idx & 15) * 4;
            *(float4*)&Ws[d][k4] =
                *(const float4*)(W + (size_t)(d0 + d) * D_MODEL + k0 + k4);
        }
        __syncthreads();
        #pragma unroll
        for (int dd = 0; dd < 32; ++dd) {
            const float2 a2 = *(const float2*)&Cs[dd][ty * 2];
            const double a0 = (double)a2.x, a1 = (double)a2.y;
            const float4 b4 = *(const float4*)&Ws[dd][tx * 4];
            const double b[4] = {(double)b4.x, (double)b4.y, (double)b4.z, (double)b4.w};
            #pragma unroll
            for (int j = 0; j < 4; ++j) { acc[0][j] += a0 * b[j]; acc[1][j] += a1 * b[j]; }
        }
        __syncthreads();
    }
    #pragma unroll
    for (int i = 0; i < 2; ++i) {
        const int e = e0 + ty * 2 + i;
        #pragma unroll
        for (int j = 0; j < 4; ++j)
            Mp[(size_t)e * D_MODEL + k0 + tx * 4 + j] = acc[i][j];
    }
}

// ---------------------------------------------------------------------------
// Kernel A2: combine D-halves -> M64, emit bf16 split Mh/Ml. grid 512x256,
// 4 elems/thread.
// ---------------------------------------------------------------------------
__global__ __launch_bounds__(256) void cw_combine(
    const double* __restrict__ Mpart, double* __restrict__ M64,
    unsigned short* __restrict__ Mh, unsigned short* __restrict__ Ml)
{
    const int i4 = ((int)blockIdx.x * 256 + (int)threadIdx.x) * 4;
    const double* p0 = Mpart;
    const double* p1 = Mpart + (size_t)NUM_EXPERTS * D_MODEL;
    unsigned short hi[4], lo[4];
    #pragma unroll
    for (int u = 0; u < 4; ++u) {
        const double v = p0[i4 + u] + p1[i4 + u];
        M64[i4 + u] = v;
        const float f = (float)v;
        hi[u] = bf16_rne(f);
        lo[u] = bf16_rne(f - bf16_f32(hi[u]));
    }
    uint2 wh, wl;
    wh.x = (unsigned)hi[0] | ((unsigned)hi[1] << 16);
    wh.y = (unsigned)hi[2] | ((unsigned)hi[3] << 16);
    wl.x = (unsigned)lo[0] | ((unsigned)lo[1] << 16);
    wl.y = (unsigned)lo[2] | ((unsigned)lo[3] << 16);
    *(uint2*)(Mh + i4) = wh;
    *(uint2*)(Ml + i4) = wl;
}

// ---------------------------------------------------------------------------
// Kernel B: affinities via bf16-split MFMA (hh+hl+lh, f32 acc).
// tile 64t x 128e, BK=32, grid (256,2) = 512 blocks (2/CU, 2 waves/SIMD).
// LDS in MFMA-fragment order (lane-sequential 16B, conflict-free), true
// double-buffer (1 barrier/chunk), register prefetch 1 chunk ahead.
// ---------------------------------------------------------------------------
struct StageRegs {
    float4 ha, hb;
    uint4 mh[2], ml[2];
};

__global__ __launch_bounds__(256, 2) void affinity_mfma(
    const float* __restrict__ H, const unsigned short* __restrict__ Mh,
    const unsigned short* __restrict__ Ml,
    float* __restrict__ aff, float* __restrict__ colsumPart)
{
    // fragment-order tiles: H 4 tiles x 64 lanes x 8 shorts; M 8 tiles.
    __shared__ unsigned short sHh[2][2048], sHl[2][2048];
    __shared__ unsigned short sMh[2][4096], sMl[2][4096];

    const int tid = threadIdx.x;
    const int lane = tid & 63, wv = tid >> 6;
    const int m = lane & 15, quad = lane >> 4;
    const int t0 = (int)blockIdx.x * 64;
    const int e0 = (int)blockIdx.y * 128;

    // staging coords: thread tid handles H row grp*16+m16 octet q, and
    // M experts (grp*2+s)*16+m16 octet q.
    const int grp = tid >> 6;
    const int q   = (tid >> 4) & 3;
    const int m16 = tid & 15;

    f32x4 acc[4][2];
    #pragma unroll
    for (int i = 0; i < 4; ++i)
        #pragma unroll
        for (int j = 0; j < 2; ++j) acc[i][j] = (f32x4){0.f, 0.f, 0.f, 0.f};

    StageRegs RA, RB;

    auto loadT = [&](int kc, StageRegs& R) {
        const int kb = kc * 32 + q * 8;
        const float* hp = H + (size_t)(t0 + grp * 16 + m16) * D_MODEL + kb;
        R.ha = *(const float4*)hp;
        R.hb = *(const float4*)(hp + 4);
        #pragma unroll
        for (int s = 0; s < 2; ++s) {
            const int e = e0 + (grp * 2 + s) * 16 + m16;
            const size_t g = (size_t)e * D_MODEL + kb;
            R.mh[s] = *(const uint4*)(Mh + g);
            R.ml[s] = *(const uint4*)(Ml + g);
        }
    };
    auto stageT = [&](int b, const StageRegs& R) {
        float x[8] = {R.ha.x, R.ha.y, R.ha.z, R.ha.w, R.hb.x, R.hb.y, R.hb.z, R.hb.w};
        unsigned short hi[8], lo[8];
        #pragma unroll
        for (int u = 0; u < 8; ++u) {
            hi[u] = bf16_rne(x[u]);
            lo[u] = bf16_rne(x[u] - bf16_f32(hi[u]));
        }
        uint4 ph, pl;
        ph.x = (unsigned)hi[0] | ((unsigned)hi[1] << 16);
        ph.y = (unsigned)hi[2] | ((unsigned)hi[3] << 16);
        ph.z = (unsigned)hi[4] | ((unsigned)hi[5] << 16);
        ph.w = (unsigned)hi[6] | ((unsigned)hi[7] << 16);
        pl.x = (unsigned)lo[0] | ((unsigned)lo[1] << 16);
        pl.y = (unsigned)lo[2] | ((unsigned)lo[3] << 16);
        pl.z = (unsigned)lo[4] | ((unsigned)lo[5] << 16);
        pl.w = (unsigned)lo[6] | ((unsigned)lo[7] << 16);
        const int l = tid & 63;
        *(uint4*)&sHh[b][grp * 512 + l * 8] = ph;
        *(uint4*)&sHl[b][grp * 512 + l * 8] = pl;
        *(uint4*)&sMh[b][(grp * 2 + 0) * 512 + l * 8] = R.mh[0];
        *(uint4*)&sMh[b][(grp * 2 + 1) * 512 + l * 8] = R.mh[1];
        *(uint4*)&sMl[b][(grp * 2 + 0) * 512 + l * 8] = R.ml[0];
        *(uint4*)&sMl[b][(grp * 2 + 1) * 512 + l * 8] = R.ml[1];
    };
    auto mfmaT = [&](int b) {
        short8 ah[4], al[4], bh[2], bl[2];
        #pragma unroll
        for (int i = 0; i < 4; ++i) {
            ah[i] = *(const short8*)&sHh[b][i * 512 + lane * 8];
            al[i] = *(const short8*)&sHl[b][i * 512 + lane * 8];
        }
        #pragma unroll
        for (int j = 0; j < 2; ++j) {
            bh[j] = *(const short8*)&sMh[b][(wv * 2 + j) * 512 + lane * 8];
            bl[j] = *(const short8*)&sMl[b][(wv * 2 + j) * 512 + lane * 8];
        }
        #pragma unroll
        for (int i = 0; i < 4; ++i)
            #pragma unroll
            for (int j = 0; j < 2; ++j) {
                acc[i][j] = __builtin_amdgcn_mfma_f32_16x16x32_bf16(ah[i], bh[j], acc[i][j], 0, 0, 0);
                acc[i][j] = __builtin_amdgcn_mfma_f32_16x16x32_bf16(ah[i], bl[j], acc[i][j], 0, 0, 0);
                acc[i][j] = __builtin_amdgcn_mfma_f32_16x16x32_bf16(al[i], bh[j], acc[i][j], 0, 0, 0);
            }
    };

    loadT(0, RA);
    stageT(0, RA);
    loadT(1, RB);
    __syncthreads();

    for (int kc = 0; kc < 64; kc += 2) {
        stageT(1, RB);                        // chunk kc+1 -> buf1
        if (kc + 2 < 64) loadT(kc + 2, RA);   // prefetch
        mfmaT(0);                             // chunk kc
        __syncthreads();
        if (kc + 2 < 64) stageT(0, RA);       // chunk kc+2 -> buf0
        if (kc + 3 < 64) loadT(kc + 3, RB);   // prefetch
        mfmaT(1);                             // chunk kc+1
        __syncthreads();
    }

    // epilogue: aff stores + sigmoid column partial sums (no atomics)
    #pragma unroll
    for (int j = 0; j < 2; ++j) {
        const int el = wv * 32 + j * 16 + m;   // local expert in [0,128)
        const int e = e0 + el;
        float colsum = 0.f;
        #pragma unroll
        for (int i = 0; i < 4; ++i) {
            const int tbase = t0 + i * 16 + quad * 4;
            #pragma unroll
            for (int r = 0; r < 4; ++r) {
                const float v = acc[i][j][r];
                aff[(size_t)(tbase + r) * NUM_EXPERTS + e] = v;
                colsum += 1.f / (1.f + expf(-v));
            }
        }
        colsum += __shfl_xor(colsum, 16, 64);
        colsum += __shfl_xor(colsum, 32, 64);
        if (quad == 0)
            colsumPart[((size_t)blockIdx.y * 256 + blockIdx.x) * 128 + el] = colsum;
    }
}

// ---------------------------------------------------------------------------
// Kernel C: fast top-9 (f32) on packed u64 keys + margin test.
// ---------------------------------------------------------------------------
__global__ __launch_bounds__(256) void topk_margin(
    const float* __restrict__ aff, const float* __restrict__ bias,
    float* __restrict__ out_idx, float* __restrict__ out_w,
    int* __restrict__ nmarg, int* __restrict__ list,
    int* __restrict__ ncand, int* __restrict__ cand)
{
    const int lane = threadIdx.x & 63;
    const int wv = threadIdx.x >> 6;
    const int t = blockIdx.x * 4 + wv;

    const float4 av = *(const float4*)(aff + (size_t)t * NUM_EXPERTS + lane * 4);
    const float4 bv = *(const float4*)(bias + lane * 4);
    float g[4], s0[4];
    g[0] = 1.f / (1.f + expf(-av.x)); s0[0] = g[0] + bv.x;
    g[1] = 1.f / (1.f + expf(-av.y)); s0[1] = g[1] + bv.y;
    g[2] = 1.f / (1.f + expf(-av.z)); s0[2] = g[2] + bv.z;
    g[3] = 1.f / (1.f + expf(-av.w)); s0[3] = g[3] + bv.w;

    unsigned long long kw[4];
    #pragma unroll
    for (int j = 0; j < 4; ++j)
        kw[j] = ((unsigned long long)ford(s0[j]) << 32)
              | (unsigned long long)(0xFFFFFFFFu - (unsigned)(lane * 4 + j));

    float wsum = 0.f, my_g = 0.f, prevs = 0.f, minGap = 1e30f, s8 = 0.f;
    int my_i = 0;

    #pragma unroll
    for (int it = 0; it < 9; ++it) {
        unsigned long long bk = kw[0];
        if (kw[1] > bk) bk = kw[1];
        if (kw[2] > bk) bk = kw[2];
        if (kw[3] > bk) bk = kw[3];
        #pragma unroll
        for (int off = 1; off < 64; off <<= 1) {
            const unsigned long long ok = __shfl_xor(bk, off, 64);
            if (ok > bk) bk = ok;
        }
        const unsigned o = (unsigned)(bk >> 32);
        const float sv = finv(o);
        const int e = (int)(0xFFFFFFFFu - (unsigned)(bk & 0xFFFFFFFFu));
        const int ej = e & 3, el = e >> 2;
        const float gl = (ej == 0) ? g[0] : (ej == 1) ? g[1] : (ej == 2) ? g[2] : g[3];
        const float gv = __shfl(gl, el, 64);
        if (it < TOP_K) {
            wsum += gv;
            if (lane == it) { my_i = e; my_g = gv; }
            if (it == 7) s8 = sv;
        }
        if (it > 0) minGap = fminf(minGap, prevs - sv);
        prevs = sv;
        if (lane == el) {
            if (ej == 0) kw[0] = 0ull; else if (ej == 1) kw[1] = 0ull;
            else if (ej == 2) kw[2] = 0ull; else kw[3] = 0ull;
        }
    }

    if (minGap < MARGIN) {
        int pos = 0;
        if (lane == 0) pos = atomicAdd(nmarg, 1);
        pos = __shfl(pos, 0, 64);
        const float thresh = s8 - MARGIN;
        int base = 0;
        #pragma unroll
        for (int j = 0; j < 4; ++j) {
            const bool c = (s0[j] >= thresh);
            const unsigned long long mk = __ballot(c);
            const int mypos = base + __popcll(mk & ((1ull << lane) - 1ull));
            if (c && mypos < 64) cand[(size_t)pos * 64 + mypos] = lane * 4 + j;
            base += (int)__popcll(mk);
        }
        if (lane == 0) { list[pos] = t; ncand[pos] = min(base, 64); }
    } else {
        const float inv = 1.f / (wsum + 1e-10f);
        if (lane < TOP_K) {
            out_idx[(size_t)t * TOP_K + lane] = (float)my_i;
            out_w[(size_t)t * TOP_K + lane] = my_g * inv;
        }
    }
}

// ---------------------------------------------------------------------------
// Kernel R: candidate-set f64 recheck.
// ---------------------------------------------------------------------------
__global__ __launch_bounds__(256) void recheck2(
    const float* __restrict__ H, const double* __restrict__ M64,
    const float* __restrict__ bias, const int* __restrict__ list,
    const int* __restrict__ ncand, const int* __restrict__ cand,
    const int* __restrict__ nmarg, float* __restrict__ out_idx,
    float* __restrict__ out_w)
{
    __shared__ float hsf[D_MODEL];
    __shared__ double sg[64], ssc[64];

    const int n = *nmarg;
    const int lane = threadIdx.x & 63, wv = threadIdx.x >> 6;

    for (int i = (int)blockIdx.x; i < n; i += (int)gridDim.x) {
        const int t = list[i];
        const int nc = ncand[i];

        for (int qd = threadIdx.x; qd < D_MODEL / 4; qd += 256)
            *(float4*)&hsf[qd * 4] = *(const float4*)(H + (size_t)t * D_MODEL + qd * 4);
        __syncthreads();

        for (int c = wv; c < nc; c += 4) {
            const int e = cand[(size_t)i * 64 + c];
            const double* mrow = M64 + (size_t)e * D_MODEL;
            double acc = 0.0;
            #pragma unroll 8
            for (int j = 0; j < 32; ++j) {
                const int k = lane + 64 * j;
                acc = fma((double)hsf[k], mrow[k], acc);
            }
            #pragma unroll
            for (int off = 1; off < 64; off <<= 1) acc += __shfl_xor(acc, off, 64);
            if (lane == 0) {
                const double gg = 1.0 / (1.0 + exp(-acc));
                sg[c] = gg;
                ssc[c] = gg + (double)bias[e];
            }
        }
        __syncthreads();

        if (wv == 0) {
            double s = -1e300, g = 0.0;
            int id = 1 << 20;
            if (lane < nc) { s = ssc[lane]; g = sg[lane]; id = cand[(size_t)i * 64 + lane]; }

            double wsum = 0.0, my_g = 0.0;
            int my_i = 0;
            for (int it = 0; it < TOP_K; ++it) {
                double bs = s, bg = g; int bi = id;
                #pragma unroll
                for (int off = 1; off < 64; off <<= 1) {
                    const double os = __shfl_xor(bs, off, 64);
                    const double og = __shfl_xor(bg, off, 64);
                    const int    oi = __shfl_xor(bi, off, 64);
                    if (os > bs || (os == bs && oi < bi)) { bs = os; bg = og; bi = oi; }
                }
                wsum += bg;
                if (lane == it) { my_i = bi; my_g = bg; }
                if (id == bi) s = -1e300;
            }
            const double inv = 1.0 / (wsum + 1e-10);
            if (lane < TOP_K) {
                out_idx[(size_t)t * TOP_K + lane] = (float)my_i;
                out_w[(size_t)t * TOP_K + lane] = (float)(my_g * inv);
            }
        }
        __syncthreads();
    }
}

// ---------------------------------------------------------------------------
// Kernel H: histogram out_idx -> counts; reduce colsumPart -> sumP.
// grid 64 x 256.
// ---------------------------------------------------------------------------
__global__ __launch_bounds__(256) void hist_reduce(
    const float* __restrict__ out_idx, const float* __restrict__ colsumPart,
    int* __restrict__ counts, double* __restrict__ sumP)
{
    __shared__ int h[NUM_EXPERTS];
    const int tid = threadIdx.x;
    const int lane = tid & 63, wv = tid >> 6;
    h[tid] = 0;
    __syncthreads();
    for (int i = (int)blockIdx.x * 256 + tid; i < T_TOKENS * TOP_K; i += 64 * 256)
        atomicAdd(&h[(int)out_idx[i]], 1);
    __syncthreads();
    if (h[tid] != 0) atomicAdd(&counts[tid], h[tid]);

    const int e = (int)blockIdx.x * 4 + wv;
    const int half = e >> 7, el = e & 127;
    float ps = 0.f;
    for (int p = lane; p < 256; p += 64)
        ps += colsumPart[((size_t)half * 256 + p) * 128 + el];
    #pragma unroll
    for (int off = 1; off < 64; off <<= 1) ps += __shfl_xor(ps, off, 64);
    if (lane == 0) sumP[e] = (double)ps;
}

// ---------------------------------------------------------------------------
// Kernel D: balance loss
// ---------------------------------------------------------------------------
__global__ __launch_bounds__(256) void loss_f64(
    const double* __restrict__ sumP, const int* __restrict__ counts,
    float* __restrict__ out_loss)
{
    __shared__ double red[256];
    const int e = threadIdx.x;
    red[e] = (double)counts[e] * sumP[e];
    __syncthreads();
    #pragma unroll
    for (int sft = 128; sft > 0; sft >>= 1) {
        if (e < sft) red[e] += red[e + sft];
        __syncthreads();
    }
    if (e == 0) {
        const double denom = (double)T_TOKENS * (double)TOP_K * (double)T_TOKENS;
        out_loss[0] = (float)(0.001 * ((double)NUM_EXPERTS / (double)TOP_K) * red[0] / denom);
    }
}

extern "C" void kernel_launch(void* const* d_in, const int* in_sizes, int n_in,
                              void* d_out, int out_size, void* d_ws, size_t ws_size,
                              hipStream_t stream) {
    (void)in_sizes; (void)n_in; (void)out_size; (void)ws_size;
    const float* hidden = (const float*)d_in[0];
    const float* W      = (const float*)d_in[1];
    const float* C      = (const float*)d_in[2];
    const float* bias   = (const float*)d_in[3];
    float* out = (float*)d_out;
    char* ws   = (char*)d_ws;

    double*         M64    = (double*)(ws + WS_M64_B);
    unsigned short* Mh     = (unsigned short*)(ws + WS_MH_B);
    unsigned short* Ml     = (unsigned short*)(ws + WS_ML_B);
    double*         sumP   = (double*)(ws + WS_SUMP_B);
    int*            counts = (int*)(ws + WS_CNT_B);
    int*            nmarg  = (int*)(ws + WS_NMARG_B);
    int*            list   = (int*)(ws + WS_LIST_B);
    int*            ncand  = (int*)(ws + WS_NCAND_B);
    int*            cand   = (int*)(ws + WS_CAND_B);
    float*          csp    = (float*)(ws + WS_CSP_B);
    double*         Mpart  = (double*)(ws + WS_MP_B);

    hipMemsetAsync(ws + WS_CNT_B, 0, NUM_EXPERTS * 4 + 16, stream);

    cw_gemm_part<<<dim3(D_MODEL / 64, NUM_EXPERTS / 32, 2), 256, 0, stream>>>(C, W, Mpart);
    cw_combine<<<dim3(NUM_EXPERTS * D_MODEL / 1024), 256, 0, stream>>>(Mpart, M64, Mh, Ml);

    affinity_mfma<<<dim3(T_TOKENS / 64, 2), 256, 0, stream>>>(hidden, Mh, Ml, out + OUT_AFF, csp);

    topk_margin<<<dim3(T_TOKENS / 4), 256, 0, stream>>>(
        out + OUT_AFF, bias, out + OUT_IDX, out + OUT_W, nmarg, list, ncand, cand);

    recheck2<<<dim3(2048), 256, 0, stream>>>(
        hidden, M64, bias, list, ncand, cand, nmarg, out + OUT_IDX, out + OUT_W);

    hist_reduce<<<dim3(64), 256, 0, stream>>>(out + OUT_IDX, csp, counts, sumP);

    loss_f64<<<dim3(1), 256, 0, stream>>>(sumP, counts, out + OUT_LOSS);
}